// Round 2
// 742.526 us; speedup vs baseline: 1.1647x; 1.1647x over previous
//
#include <hip/hip_runtime.h>
#include <math.h>

#define TOKENS  16384
#define HIDDEN  4096
#define NEXPERT 256
#define NGROUP  8
#define GSIZE   32
#define TOPKG   4
#define TOPK    8
#define RSCALE  2.5f

// One fused kernel: block = 64 tokens x ALL 256 experts, full K, routing in
// epilogue. Round-4/5 change: 512-thread block (8 waves -> 2 waves/EU) with an
// 8x4 per-thread micro-tile (acc 64->32 VGPRs). Rationale: round-3 counters
// showed VALUBusy 49% / Occupancy 10.7% -- the waves_per_eu(1,1) pin left one
// wave/SIMD with nothing to hide ds_read->fma latency or barrier drain. The
// smaller accumulator fits the 256-VGPR budget of waves_per_eu(2,2), so we get
// 2 waves/EU with zero spill. fp32 ascending-k fmaf chain per logit is
// BIT-IDENTICAL to the passing baseline (top-k order must stay correlated
// with the reference). Round 5 = identical resubmit of round 4 (round-4 bench
// died to an infra container failure before running; audit found no fault/hang
// path in the kernel).
#define BM   64
#define BK   16
#define LDA  68    // A-tile leading pad: staging writes 2-way aliased (free)
#define LDB  260   // B-tile leading pad
#define NTHR 512

__device__ __forceinline__ float sigmoid_acc(float x) {
    return 1.0f / (1.0f + expf(-x));   // accurate expf: top-k order must match ref
}

__global__ __launch_bounds__(NTHR, 2) __attribute__((amdgpu_waves_per_eu(2, 2)))
void moe_gate_fused(const float* __restrict__ A,      // [TOKENS, HIDDEN]
                    const float* __restrict__ B,      // [NEXPERT, HIDDEN]
                    const float* __restrict__ bias,   // [NEXPERT]
                    float* __restrict__ out_idx,
                    float* __restrict__ out_w,
                    float* __restrict__ out_logits)
{
    __shared__ float As[2][BK * LDA];          // As[k][m], 64 rows
    __shared__ float Bs[2][BK * LDB];          // Bs[k][n], 256 rows
    __shared__ float gsum[BM][NGROUP + 1];

    const int tid = threadIdx.x;
    const int m0  = blockIdx.x * BM;

    // ---- staging map (512 threads) ----
    // A: 64x16 tile = 256 float4 -> 512 threads load 1 float2 each.
    //    8 lanes cover 64B of one row (coalesced).
    const int ar_a = tid >> 3;          // 0..63  A row
    const int kh   = tid & 7;           // float2 column pair (k = kh*2, kh*2+1)
    // B: 256x16 tile = 1024 float4 -> 2 float4/thread (8 contiguous floats
    //    of one row; 2 lanes cover 64B of a row).
    const int ar_b = tid >> 1;          // 0..255 B row
    const int q0   = (tid & 1) * 2;     // k-quad pair {0,1} or {2,3}

    const float* Ag = A + (long)(m0 + ar_a) * HIDDEN + kh * 2;
    const float* Bg = B + (long)ar_b * HIDDEN + q0 * 4;

    // ---- compute map: 8x64 thread grid, 8x4 micro-tile ----
    // A-fragment address is wave-uniform (tr constant per wave) -> pure LDS
    // broadcast. B-fragment: 64 lanes read one contiguous 1KiB line ->
    // conflict-free. B LDS demand = 0.5 B/FMA = 64 B/cy/CU at full VALU rate
    // (half of LDS peak), so LDS is not the new wall.
    const int tr   = tid >> 6;   // 0..7
    const int tc   = tid & 63;   // 0..63
    const int row0 = tr * 8;
    const int c0   = tc * 4;

    float2 qa;
    float4 pb0, pb1;

    // prefetch tile 0
    qa  = *(const float2*)(Ag);
    pb0 = *(const float4*)(Bg);
    pb1 = *(const float4*)(Bg + 4);

    // stage tile 0 -> buffer 0
    {
        float* as = As[0];
        as[(kh * 2 + 0) * LDA + ar_a] = qa.x;
        as[(kh * 2 + 1) * LDA + ar_a] = qa.y;
        float* bs = Bs[0];
        bs[(q0 * 4 + 0) * LDB + ar_b] = pb0.x;
        bs[(q0 * 4 + 1) * LDB + ar_b] = pb0.y;
        bs[(q0 * 4 + 2) * LDB + ar_b] = pb0.z;
        bs[(q0 * 4 + 3) * LDB + ar_b] = pb0.w;
        bs[(q0 * 4 + 4) * LDB + ar_b] = pb1.x;
        bs[(q0 * 4 + 5) * LDB + ar_b] = pb1.y;
        bs[(q0 * 4 + 6) * LDB + ar_b] = pb1.z;
        bs[(q0 * 4 + 7) * LDB + ar_b] = pb1.w;
    }
    __syncthreads();

    float acc[8][4] = {};

    const int NKT = HIDDEN / BK;   // 256
    for (int kt = 0; kt < NKT; ++kt) {
        const int cur = kt & 1;

        if (kt + 1 < NKT) {
            const int ko = (kt + 1) * BK;
            qa  = *(const float2*)(Ag + ko);
            pb0 = *(const float4*)(Bg + ko);
            pb1 = *(const float4*)(Bg + ko + 4);
        }

        const float* as = As[cur];
        const float* bs = Bs[cur];
        #pragma unroll
        for (int k = 0; k < BK; ++k) {
            float4 a0 = *(const float4*)(as + k * LDA + row0);       // wave-uniform bcast
            float4 a1 = *(const float4*)(as + k * LDA + row0 + 4);   // wave-uniform bcast
            float4 b0 = *(const float4*)(bs + k * LDB + c0);         // contiguous, conflict-free
            float av[8] = {a0.x, a0.y, a0.z, a0.w, a1.x, a1.y, a1.z, a1.w};
            float bv[4] = {b0.x, b0.y, b0.z, b0.w};
            #pragma unroll
            for (int i = 0; i < 8; ++i)
                #pragma unroll
                for (int j = 0; j < 4; ++j)
                    acc[i][j] = fmaf(av[i], bv[j], acc[i][j]);
        }

        if (kt + 1 < NKT) {
            float* as_w = As[cur ^ 1];
            as_w[(kh * 2 + 0) * LDA + ar_a] = qa.x;
            as_w[(kh * 2 + 1) * LDA + ar_a] = qa.y;
            float* bs_w = Bs[cur ^ 1];
            bs_w[(q0 * 4 + 0) * LDB + ar_b] = pb0.x;
            bs_w[(q0 * 4 + 1) * LDB + ar_b] = pb0.y;
            bs_w[(q0 * 4 + 2) * LDB + ar_b] = pb0.z;
            bs_w[(q0 * 4 + 3) * LDB + ar_b] = pb0.w;
            bs_w[(q0 * 4 + 4) * LDB + ar_b] = pb1.x;
            bs_w[(q0 * 4 + 5) * LDB + ar_b] = pb1.y;
            bs_w[(q0 * 4 + 6) * LDB + ar_b] = pb1.z;
            bs_w[(q0 * 4 + 7) * LDB + ar_b] = pb1.w;
        }
        __syncthreads();
    }

    // ---- epilogue: write logits (coalesced float4) ----
    #pragma unroll
    for (int i = 0; i < 8; ++i) {
        long row = m0 + row0 + i;
        *(float4*)(out_logits + row * NEXPERT + c0) =
            make_float4(acc[i][0], acc[i][1], acc[i][2], acc[i][3]);
    }
    __syncthreads();   // barrier drains vmcnt -> this block's logits visible via its L2

    // ---- routing phase A: per (token, group) top-2 of sigmoid(logit)+bias ----
    for (int task = tid; task < BM * NGROUP; task += NTHR) {
        const int tt = task >> 3;
        const int g  = task & 7;
        const float* lg = out_logits + (long)(m0 + tt) * NEXPERT + g * GSIZE;
        const float* bp = bias + g * GSIZE;
        float m1 = -INFINITY, m2 = -INFINITY;
        #pragma unroll
        for (int j4 = 0; j4 < GSIZE / 4; ++j4) {
            float4 l = *(const float4*)(lg + j4 * 4);
            float4 b = *(const float4*)(bp + j4 * 4);
            float vv[4] = {sigmoid_acc(l.x) + b.x, sigmoid_acc(l.y) + b.y,
                           sigmoid_acc(l.z) + b.z, sigmoid_acc(l.w) + b.w};
            #pragma unroll
            for (int c = 0; c < 4; ++c) {
                float x = vv[c];
                if (x > m1) { m2 = m1; m1 = x; }
                else if (x > m2) { m2 = x; }
            }
        }
        gsum[tt][g] = m1 + m2;
    }
    __syncthreads();

    // ---- routing phase B: one worker per token ----
    if (tid < BM) {
        const long tok = m0 + tid;
        const float* lg = out_logits + tok * NEXPERT;

        float gs[NGROUP];
        #pragma unroll
        for (int g = 0; g < NGROUP; ++g) gs[g] = gsum[tid][g];

        unsigned selmask = 0;
        #pragma unroll
        for (int r = 0; r < TOPKG; ++r) {
            float best = -INFINITY; int bi = 0;
            #pragma unroll
            for (int g = 0; g < NGROUP; ++g) {
                bool taken = (selmask >> g) & 1u;
                if (!taken && gs[g] > best) { best = gs[g]; bi = g; }
            }
            selmask |= 1u << bi;
        }

        float rv[TOPK]; int ri[TOPK];
        #pragma unroll
        for (int k = 0; k < TOPK; ++k) { rv[k] = -INFINITY; ri[k] = 0; }

        for (int g = 0; g < NGROUP; ++g) {
            if (!((selmask >> g) & 1u)) continue;
            #pragma unroll 4
            for (int j = 0; j < GSIZE; ++j) {
                int e = g * GSIZE + j;
                float v = sigmoid_acc(lg[e]) + bias[e];
                if (v > rv[TOPK - 1]) {
                    rv[TOPK - 1] = v; ri[TOPK - 1] = e;
                    #pragma unroll
                    for (int q = TOPK - 1; q > 0; --q) {
                        if (rv[q] > rv[q - 1]) {
                            float tv = rv[q]; rv[q] = rv[q - 1]; rv[q - 1] = tv;
                            int   ti = ri[q]; ri[q] = ri[q - 1]; ri[q - 1] = ti;
                        }
                    }
                }
            }
        }

        float pv[TOPK]; float sum = 0.0f;
        #pragma unroll
        for (int k = 0; k < TOPK; ++k) { pv[k] = rv[k] - bias[ri[k]]; sum += pv[k]; }
        float denom = sum + 1e-20f;

        #pragma unroll
        for (int k = 0; k < TOPK; ++k) {
            out_idx[tok * TOPK + k] = (float)ri[k];
            out_w[tok * TOPK + k]   = pv[k] / denom * RSCALE;
        }
    }
}

// ---------------- launch ----------------
extern "C" void kernel_launch(void* const* d_in, const int* in_sizes, int n_in,
                              void* d_out, int out_size, void* d_ws, size_t ws_size,
                              hipStream_t stream) {
    const float* hidden = (const float*)d_in[0];
    const float* gate_w = (const float*)d_in[1];
    const float* bias   = (const float*)d_in[2];

    float* out = (float*)d_out;
    float* out_idx    = out;
    float* out_w      = out + (long)TOKENS * TOPK;
    float* out_logits = out + (long)TOKENS * TOPK * 2;

    moe_gate_fused<<<TOKENS / BM, NTHR, 0, stream>>>(
        hidden, gate_w, bias, out_idx, out_w, out_logits);
}